// Round 1
// baseline (303.099 us; speedup 1.0000x reference)
//
#include <hip/hip_runtime.h>
#include <stdint.h>

#define NB 2
#define NS 2048
#define NHID 1024
#define NHEADS 4
#define DHEAD 256
#define NP 128            // DHEAD/2
#define QK_SCALE 0.0625f  // HD^-0.5

typedef unsigned short ushort_t;
typedef __bf16 bf16x8 __attribute__((ext_vector_type(8)));
typedef float floatx4 __attribute__((ext_vector_type(4)));
typedef short shortx8 __attribute__((ext_vector_type(8)));
typedef unsigned short ushortx4 __attribute__((ext_vector_type(4)));

__device__ __forceinline__ float bf2f(ushort_t u) {
    unsigned int x = ((unsigned int)u) << 16;
    return __builtin_bit_cast(float, x);
}
__device__ __forceinline__ ushort_t f2bf(float f) {
    unsigned int u = __builtin_bit_cast(unsigned int, f);
    u += 0x7fff + ((u >> 16) & 1);   // RNE
    return (ushort_t)(u >> 16);
}

__device__ __forceinline__ floatx4 mfma16(bf16x8 a, bf16x8 b, floatx4 c) {
    return __builtin_amdgcn_mfma_f32_16x16x32_bf16(a, b, c, 0, 0, 0);
}

__device__ __forceinline__ void gload_lds16(const void* g, void* l) {
    __builtin_amdgcn_global_load_lds(
        (const __attribute__((address_space(1))) void*)g,
        (__attribute__((address_space(3))) void*)l, 16, 0, 0);
}

// ---------------- cast fp32 -> bf16 ----------------
__global__ __launch_bounds__(256) void cast_kernel(const float* __restrict__ in,
                                                   ushort_t* __restrict__ out, int n4) {
    int i = blockIdx.x * 256 + threadIdx.x;
    if (i < n4) {
        float4 v = ((const float4*)in)[i];
        ushortx4 o = { f2bf(v.x), f2bf(v.y), f2bf(v.z), f2bf(v.w) };
        ((ushortx4*)out)[i] = o;
    }
}

// ---------------- GEMM: C[M,N] = A[M,K] * Bt[N,K]^T  (bf16 in, fp32 acc) ----------------
// 128x128 tile, BK=32, 256 threads (2x2 waves, 4x4 16x16 frags each). m97 structure.
template <bool OUT_BF16>
__global__ __launch_bounds__(256) void gemm_bt(const ushort_t* __restrict__ A,
                                               const ushort_t* __restrict__ Bt,
                                               void* __restrict__ Cout,
                                               int M, int N, int K) {
    __shared__ ushort_t sA[128 * 32];
    __shared__ ushort_t sB[128 * 32];
    const int t = threadIdx.x;
    const int m0 = blockIdx.y * 128;
    const int n0 = blockIdx.x * 128;
    const int w = t >> 6, l = t & 63;
    const int wm = (w >> 1) * 64, wn = (w & 1) * 64;
    const int lc = l & 15, lq = l >> 4;

    floatx4 acc[4][4];
#pragma unroll
    for (int i = 0; i < 4; i++)
#pragma unroll
        for (int j = 0; j < 4; j++) acc[i][j] = (floatx4){0.f, 0.f, 0.f, 0.f};

    // staging: 512 chunks of 8 elems (16B); thread t does chunks t and t+256
    const int r0 = t >> 2, c8 = (t & 3) * 8;
    const ushort_t* Ag0 = A + (size_t)(m0 + r0) * K + c8;
    const ushort_t* Ag1 = A + (size_t)(m0 + r0 + 64) * K + c8;
    const ushort_t* Bg0 = Bt + (size_t)(n0 + r0) * K + c8;
    const ushort_t* Bg1 = Bt + (size_t)(n0 + r0 + 64) * K + c8;
    ushort_t* lA0 = &sA[(size_t)t * 8];
    ushort_t* lA1 = &sA[(size_t)(t + 256) * 8];
    ushort_t* lB0 = &sB[(size_t)t * 8];
    ushort_t* lB1 = &sB[(size_t)(t + 256) * 8];

    for (int kk = 0; kk < K; kk += 32) {
        __syncthreads();
        gload_lds16(Ag0 + kk, lA0);
        gload_lds16(Ag1 + kk, lA1);
        gload_lds16(Bg0 + kk, lB0);
        gload_lds16(Bg1 + kk, lB1);
        __syncthreads();
        bf16x8 af[4], bfv[4];
#pragma unroll
        for (int i = 0; i < 4; i++)
            af[i] = *(const bf16x8*)&sA[(wm + i * 16 + lc) * 32 + lq * 8];
#pragma unroll
        for (int j = 0; j < 4; j++)
            bfv[j] = *(const bf16x8*)&sB[(wn + j * 16 + lc) * 32 + lq * 8];
#pragma unroll
        for (int i = 0; i < 4; i++)
#pragma unroll
            for (int j = 0; j < 4; j++)
                acc[i][j] = mfma16(af[i], bfv[j], acc[i][j]);
    }

#pragma unroll
    for (int i = 0; i < 4; i++) {
        int row = m0 + wm + i * 16 + lq * 4;
#pragma unroll
        for (int j = 0; j < 4; j++) {
            int col = n0 + wn + j * 16 + lc;
#pragma unroll
            for (int r = 0; r < 4; r++) {
                if constexpr (OUT_BF16)
                    ((ushort_t*)Cout)[(size_t)(row + r) * N + col] = f2bf(acc[i][j][r]);
                else
                    ((float*)Cout)[(size_t)(row + r) * N + col] = acc[i][j][r];
            }
        }
    }
}

// ---------------- RoPE + split qkv -> Q (scaled), K, V  [b][h][s][d] ----------------
__global__ __launch_bounds__(256) void rope_split(const ushort_t* __restrict__ qkv,
                                                  const float* __restrict__ fre,
                                                  const float* __restrict__ fim,
                                                  ushort_t* __restrict__ Q,
                                                  ushort_t* __restrict__ Kk,
                                                  ushort_t* __restrict__ V) {
    const int rrow = blockIdx.x;          // b*NS + s
    const int b = rrow / NS, s = rrow % NS;
    const int t = threadIdx.x;
    const ushort_t* src = qkv + (size_t)rrow * 3072;
#pragma unroll
    for (int ii = 0; ii < 2; ii++) {
        int idx = t + ii * 256;           // 0..511 pair index over (h,p)
        int h = idx >> 7, p = idx & 127;
        float c = fre[s * NP + p], si = fim[s * NP + p];
        size_t dsto = ((size_t)(b * NHEADS + h) * NS + s) * DHEAD + 2 * p;
        float re = bf2f(src[h * DHEAD + 2 * p]);
        float im = bf2f(src[h * DHEAD + 2 * p + 1]);
        Q[dsto] = f2bf((re * c - im * si) * QK_SCALE);
        Q[dsto + 1] = f2bf((re * si + im * c) * QK_SCALE);
        re = bf2f(src[NHID + h * DHEAD + 2 * p]);
        im = bf2f(src[NHID + h * DHEAD + 2 * p + 1]);
        Kk[dsto] = f2bf(re * c - im * si);
        Kk[dsto + 1] = f2bf(re * si + im * c);
    }
#pragma unroll
    for (int ii = 0; ii < 4; ii++) {
        int e = t + ii * 256;
        int h = e >> 8, d = e & 255;
        V[((size_t)(b * NHEADS + h) * NS + s) * DHEAD + d] = src[2048 + e];
    }
}

// ---------------- transpose V[bh][s][d] -> Vt[bh][d][s] ----------------
__global__ __launch_bounds__(256) void transpose_v(const ushort_t* __restrict__ V,
                                                   ushort_t* __restrict__ Vt) {
    __shared__ ushort_t tile[32][33];
    const int bh = blockIdx.z;
    const int s0 = blockIdx.x * 32, d0 = blockIdx.y * 32;
    const int x = threadIdx.x & 31, y = threadIdx.x >> 5;
    const ushort_t* src = V + (size_t)bh * NS * DHEAD;
    ushort_t* dst = Vt + (size_t)bh * NS * DHEAD;
#pragma unroll
    for (int i = 0; i < 4; i++) {
        int yy = y + i * 8;
        tile[yy][x] = src[(size_t)(s0 + yy) * DHEAD + d0 + x];
    }
    __syncthreads();
#pragma unroll
    for (int i = 0; i < 4; i++) {
        int yy = y + i * 8;
        dst[(size_t)(d0 + yy) * NS + s0 + x] = tile[x][yy];
    }
}

// ---------------- flash attention ----------------
// grid (qt=32, h=4, b=2), block 256 (4 waves x 16 q-rows), BKV=32 keys/chunk.
#define BQ 64
#define BKV 32
#define KPAD 264   // 256+8 elems; 528B = 33*16 (b128-aligned, 2-way banks)
#define VPAD 40    // 32+8 elems; 80B = 5*16
#define PPAD 40

__global__ __launch_bounds__(256) void flash_attn(const ushort_t* __restrict__ Q,
                                                  const ushort_t* __restrict__ K,
                                                  const ushort_t* __restrict__ Vt,
                                                  ushort_t* __restrict__ O) {
    __shared__ ushort_t sK[BKV * KPAD];        // [key][d]
    __shared__ ushort_t sV[DHEAD * VPAD];      // [d][key]
    __shared__ ushort_t sP[4][16 * PPAD];      // per-wave [row][key]

    const int qt = blockIdx.x, h = blockIdx.y, b = blockIdx.z;
    const int t = threadIdx.x, w = t >> 6, l = t & 63;
    const int lc = l & 15, lq = l >> 4;
    const int bh = b * NHEADS + h;
    const size_t base = (size_t)bh * NS * DHEAD;
    const int q0 = qt * BQ;
    const int qrow_g = q0 + w * 16 + lq * 4;   // +r = this lane's rows

    // Q fragments in registers: wave w covers q-rows [q0+w*16, +16)
    bf16x8 qf[8];
    {
        const ushort_t* qrow = Q + base + (size_t)(q0 + w * 16 + lc) * DHEAD + lq * 8;
#pragma unroll
        for (int dk = 0; dk < 8; dk++) qf[dk] = *(const bf16x8*)(qrow + dk * 32);
    }

    floatx4 accO[16];
#pragma unroll
    for (int j = 0; j < 16; j++) accO[j] = (floatx4){0.f, 0.f, 0.f, 0.f};
    float mrun[4], lrun[4];
#pragma unroll
    for (int r = 0; r < 4; r++) { mrun[r] = -__builtin_inff(); lrun[r] = 0.f; }

    const int nch = 2 * qt + 2;
    for (int kc = 0; kc < nch; kc++) {
        const int kb = kc * BKV;
        __syncthreads();
        // stage K chunk: 32 rows x 256 d
#pragma unroll
        for (int j = 0; j < 4; j++) {
            int c = t + j * 256;
            int krow = c >> 5, cc = (c & 31) * 8;
            const ushort_t* g = K + base + (size_t)(kb + krow) * DHEAD + cc;
            *(shortx8*)&sK[krow * KPAD + cc] = *(const shortx8*)g;
        }
        // stage Vt chunk: 256 d-rows x 32 keys
#pragma unroll
        for (int j = 0; j < 4; j++) {
            int c = t + j * 256;
            int drow = c >> 2, cc = (c & 3) * 8;
            const ushort_t* g = Vt + base + (size_t)drow * NS + kb + cc;
            *(shortx8*)&sV[drow * VPAD + cc] = *(const shortx8*)g;
        }
        __syncthreads();

        // S = Q K^T (16 x 32)
        floatx4 sfr[2];
        sfr[0] = (floatx4){0.f, 0.f, 0.f, 0.f};
        sfr[1] = (floatx4){0.f, 0.f, 0.f, 0.f};
#pragma unroll
        for (int dk = 0; dk < 8; dk++) {
            bf16x8 b0 = *(const bf16x8*)&sK[lc * KPAD + dk * 32 + lq * 8];
            bf16x8 b1 = *(const bf16x8*)&sK[(16 + lc) * KPAD + dk * 32 + lq * 8];
            sfr[0] = mfma16(qf[dk], b0, sfr[0]);
            sfr[1] = mfma16(qf[dk], b1, sfr[1]);
        }
        // causal mask
#pragma unroll
        for (int j = 0; j < 2; j++) {
            int kg = kb + j * 16 + lc;
#pragma unroll
            for (int r = 0; r < 4; r++)
                if (kg > qrow_g + r) sfr[j][r] = -1e30f;
        }
        // online softmax (rows live across 16 lanes of a quad)
        float mch[4];
#pragma unroll
        for (int r = 0; r < 4; r++) mch[r] = fmaxf(sfr[0][r], sfr[1][r]);
#pragma unroll
        for (int off = 1; off < 16; off <<= 1)
#pragma unroll
            for (int r = 0; r < 4; r++) mch[r] = fmaxf(mch[r], __shfl_xor(mch[r], off));
        float alpha[4], psum[4], p0[4], p1[4];
#pragma unroll
        for (int r = 0; r < 4; r++) {
            float mnew = fmaxf(mrun[r], mch[r]);
            alpha[r] = __expf(mrun[r] - mnew);
            p0[r] = __expf(sfr[0][r] - mnew);
            p1[r] = __expf(sfr[1][r] - mnew);
            mrun[r] = mnew;
            psum[r] = p0[r] + p1[r];
        }
#pragma unroll
        for (int off = 1; off < 16; off <<= 1)
#pragma unroll
            for (int r = 0; r < 4; r++) psum[r] += __shfl_xor(psum[r], off);
#pragma unroll
        for (int r = 0; r < 4; r++) lrun[r] = lrun[r] * alpha[r] + psum[r];
#pragma unroll
        for (int j = 0; j < 16; j++)
#pragma unroll
            for (int r = 0; r < 4; r++) accO[j][r] *= alpha[r];

        // P: C-layout -> LDS -> A-layout (per-wave buffer, no barrier needed)
        ushort_t* pw = sP[w];
#pragma unroll
        for (int r = 0; r < 4; r++) {
            pw[(lq * 4 + r) * PPAD + lc] = f2bf(p0[r]);
            pw[(lq * 4 + r) * PPAD + 16 + lc] = f2bf(p1[r]);
        }
        bf16x8 ap = *(const bf16x8*)&pw[lc * PPAD + lq * 8];
        // O += P V
#pragma unroll
        for (int j = 0; j < 16; j++) {
            bf16x8 bv = *(const bf16x8*)&sV[(j * 16 + lc) * VPAD + lq * 8];
            accO[j] = mfma16(ap, bv, accO[j]);
        }
    }

    // epilogue: O[b][s][h][d] bf16
    float inv[4];
#pragma unroll
    for (int r = 0; r < 4; r++) inv[r] = 1.f / lrun[r];
#pragma unroll
    for (int r = 0; r < 4; r++) {
        size_t ro = ((size_t)(b * NS + qrow_g + r) * NHEADS + h) * DHEAD;
#pragma unroll
        for (int j = 0; j < 16; j++)
            O[ro + j * 16 + lc] = f2bf(accO[j][r] * inv[r]);
    }
}

// ---------------- launch ----------------
extern "C" void kernel_launch(void* const* d_in, const int* in_sizes, int n_in,
                              void* d_out, int out_size, void* d_ws, size_t ws_size,
                              hipStream_t stream) {
    const float* hidden = (const float*)d_in[0];
    const float* fre = (const float*)d_in[1];
    const float* fim = (const float*)d_in[2];
    // d_in[3] = mask (causal, reproduced analytically)
    const float* Wqkv = (const float*)d_in[4];
    const float* Wo = (const float*)d_in[5];

    char* ws = (char*)d_ws;
    ushort_t* hb    = (ushort_t*)(ws);                 // 4096x1024 bf16   (8 MB)
    ushort_t* wqkvb = (ushort_t*)(ws + 8388608);       // 3072x1024 bf16   (6 MB)
    ushort_t* wob   = (ushort_t*)(ws + 14680064);      // 1024x1024 bf16   (2 MB)
    ushort_t* qkvb  = (ushort_t*)(ws + 16777216);      // 4096x3072 bf16   (24 MB), dead after rope
    ushort_t* vtb   = (ushort_t*)(ws + 16777216);      // alias over qkvb  (8 MB)
    ushort_t* oattn = (ushort_t*)(ws + 25165824);      // alias over qkvb  (8 MB)
    ushort_t* qb    = (ushort_t*)(ws + 41943040);      // 8 MB
    ushort_t* kb    = (ushort_t*)(ws + 50331648);      // 8 MB
    ushort_t* vb    = (ushort_t*)(ws + 58720256);      // 8 MB  -> total 64 MB

    cast_kernel<<<4096, 256, 0, stream>>>(hidden, hb, 4096 * 1024 / 4);
    cast_kernel<<<3072, 256, 0, stream>>>(Wqkv, wqkvb, 3072 * 1024 / 4);
    cast_kernel<<<1024, 256, 0, stream>>>(Wo, wob, 1024 * 1024 / 4);

    gemm_bt<true><<<dim3(3072 / 128, 4096 / 128), 256, 0, stream>>>(
        hb, wqkvb, qkvb, 4096, 3072, 1024);

    rope_split<<<4096, 256, 0, stream>>>(qkvb, fre, fim, qb, kb, vb);
    transpose_v<<<dim3(64, 8, 8), 256, 0, stream>>>(vb, vtb);

    flash_attn<<<dim3(32, NHEADS, NB), 256, 0, stream>>>(qb, kb, vtb, oattn);

    gemm_bt<false><<<dim3(1024 / 128, 4096 / 128), 256, 0, stream>>>(
        oattn, wob, d_out, 4096, 1024, 1024);
}

// Round 2
// 259.140 us; speedup vs baseline: 1.1696x; 1.1696x over previous
//
#include <hip/hip_runtime.h>
#include <stdint.h>

#define NB 2
#define NS 2048
#define NHID 1024
#define NHEADS 4
#define DHEAD 256
#define NP 128            // DHEAD/2
#define QK_SCALE 0.0625f  // HD^-0.5

typedef unsigned short ushort_t;
typedef __bf16 bf16x8 __attribute__((ext_vector_type(8)));
typedef float floatx4 __attribute__((ext_vector_type(4)));
typedef short shortx8 __attribute__((ext_vector_type(8)));
typedef unsigned short ushortx4 __attribute__((ext_vector_type(4)));

__device__ __forceinline__ float bf2f(ushort_t u) {
    unsigned int x = ((unsigned int)u) << 16;
    return __builtin_bit_cast(float, x);
}
__device__ __forceinline__ ushort_t f2bf(float f) {
    unsigned int u = __builtin_bit_cast(unsigned int, f);
    u += 0x7fff + ((u >> 16) & 1);   // RNE
    return (ushort_t)(u >> 16);
}

__device__ __forceinline__ floatx4 mfma16(bf16x8 a, bf16x8 b, floatx4 c) {
    return __builtin_amdgcn_mfma_f32_16x16x32_bf16(a, b, c, 0, 0, 0);
}

__device__ __forceinline__ void gload_lds16(const void* g, void* l) {
    __builtin_amdgcn_global_load_lds(
        (const __attribute__((address_space(1))) void*)g,
        (__attribute__((address_space(3))) void*)l, 16, 0, 0);
}

// ---------------- cast fp32 -> bf16 ----------------
__global__ __launch_bounds__(256) void cast_kernel(const float* __restrict__ in,
                                                   ushort_t* __restrict__ out, int n4) {
    int i = blockIdx.x * 256 + threadIdx.x;
    if (i < n4) {
        float4 v = ((const float4*)in)[i];
        ushortx4 o = { f2bf(v.x), f2bf(v.y), f2bf(v.z), f2bf(v.w) };
        ((ushortx4*)out)[i] = o;
    }
}

// ---------------- GEMM: C[M,N] = A[M,K] * Bt[N,K]^T  (bf16 in, fp32 acc) ----------------
template <bool OUT_BF16>
__global__ __launch_bounds__(256) void gemm_bt(const ushort_t* __restrict__ A,
                                               const ushort_t* __restrict__ Bt,
                                               void* __restrict__ Cout,
                                               int M, int N, int K) {
    __shared__ ushort_t sA[128 * 32];
    __shared__ ushort_t sB[128 * 32];
    const int t = threadIdx.x;
    const int m0 = blockIdx.y * 128;
    const int n0 = blockIdx.x * 128;
    const int w = t >> 6, l = t & 63;
    const int wm = (w >> 1) * 64, wn = (w & 1) * 64;
    const int lc = l & 15, lq = l >> 4;

    floatx4 acc[4][4];
#pragma unroll
    for (int i = 0; i < 4; i++)
#pragma unroll
        for (int j = 0; j < 4; j++) acc[i][j] = (floatx4){0.f, 0.f, 0.f, 0.f};

    const int r0 = t >> 2, c8 = (t & 3) * 8;
    const ushort_t* Ag0 = A + (size_t)(m0 + r0) * K + c8;
    const ushort_t* Ag1 = A + (size_t)(m0 + r0 + 64) * K + c8;
    const ushort_t* Bg0 = Bt + (size_t)(n0 + r0) * K + c8;
    const ushort_t* Bg1 = Bt + (size_t)(n0 + r0 + 64) * K + c8;
    ushort_t* lA0 = &sA[(size_t)t * 8];
    ushort_t* lA1 = &sA[(size_t)(t + 256) * 8];
    ushort_t* lB0 = &sB[(size_t)t * 8];
    ushort_t* lB1 = &sB[(size_t)(t + 256) * 8];

    for (int kk = 0; kk < K; kk += 32) {
        __syncthreads();
        gload_lds16(Ag0 + kk, lA0);
        gload_lds16(Ag1 + kk, lA1);
        gload_lds16(Bg0 + kk, lB0);
        gload_lds16(Bg1 + kk, lB1);
        __syncthreads();
        bf16x8 af[4], bfv[4];
#pragma unroll
        for (int i = 0; i < 4; i++)
            af[i] = *(const bf16x8*)&sA[(wm + i * 16 + lc) * 32 + lq * 8];
#pragma unroll
        for (int j = 0; j < 4; j++)
            bfv[j] = *(const bf16x8*)&sB[(wn + j * 16 + lc) * 32 + lq * 8];
#pragma unroll
        for (int i = 0; i < 4; i++)
#pragma unroll
            for (int j = 0; j < 4; j++)
                acc[i][j] = mfma16(af[i], bfv[j], acc[i][j]);
    }

#pragma unroll
    for (int i = 0; i < 4; i++) {
        int row = m0 + wm + i * 16 + lq * 4;
#pragma unroll
        for (int j = 0; j < 4; j++) {
            int col = n0 + wn + j * 16 + lc;
#pragma unroll
            for (int r = 0; r < 4; r++) {
                if constexpr (OUT_BF16)
                    ((ushort_t*)Cout)[(size_t)(row + r) * N + col] = f2bf(acc[i][j][r]);
                else
                    ((float*)Cout)[(size_t)(row + r) * N + col] = acc[i][j][r];
            }
        }
    }
}

// ---------------- RoPE + split qkv -> Q (scaled), K, V  [b][h][s][d] ----------------
__global__ __launch_bounds__(256) void rope_split(const ushort_t* __restrict__ qkv,
                                                  const float* __restrict__ fre,
                                                  const float* __restrict__ fim,
                                                  ushort_t* __restrict__ Q,
                                                  ushort_t* __restrict__ Kk,
                                                  ushort_t* __restrict__ V) {
    const int rrow = blockIdx.x;          // b*NS + s
    const int b = rrow / NS, s = rrow % NS;
    const int t = threadIdx.x;
    const ushort_t* src = qkv + (size_t)rrow * 3072;
#pragma unroll
    for (int ii = 0; ii < 2; ii++) {
        int idx = t + ii * 256;           // 0..511 pair index over (h,p)
        int h = idx >> 7, p = idx & 127;
        float c = fre[s * NP + p], si = fim[s * NP + p];
        size_t dsto = ((size_t)(b * NHEADS + h) * NS + s) * DHEAD + 2 * p;
        float re = bf2f(src[h * DHEAD + 2 * p]);
        float im = bf2f(src[h * DHEAD + 2 * p + 1]);
        Q[dsto] = f2bf((re * c - im * si) * QK_SCALE);
        Q[dsto + 1] = f2bf((re * si + im * c) * QK_SCALE);
        re = bf2f(src[NHID + h * DHEAD + 2 * p]);
        im = bf2f(src[NHID + h * DHEAD + 2 * p + 1]);
        Kk[dsto] = f2bf(re * c - im * si);
        Kk[dsto + 1] = f2bf(re * si + im * c);
    }
#pragma unroll
    for (int ii = 0; ii < 4; ii++) {
        int e = t + ii * 256;
        int h = e >> 8, d = e & 255;
        V[((size_t)(b * NHEADS + h) * NS + s) * DHEAD + d] = src[2048 + e];
    }
}

// ---------------- transpose V[bh][s][d] -> Vt[bh][d][s] ----------------
__global__ __launch_bounds__(256) void transpose_v(const ushort_t* __restrict__ V,
                                                   ushort_t* __restrict__ Vt) {
    __shared__ ushort_t tile[32][33];
    const int bh = blockIdx.z;
    const int s0 = blockIdx.x * 32, d0 = blockIdx.y * 32;
    const int x = threadIdx.x & 31, y = threadIdx.x >> 5;
    const ushort_t* src = V + (size_t)bh * NS * DHEAD;
    ushort_t* dst = Vt + (size_t)bh * NS * DHEAD;
#pragma unroll
    for (int i = 0; i < 4; i++) {
        int yy = y + i * 8;
        tile[yy][x] = src[(size_t)(s0 + yy) * DHEAD + d0 + x];
    }
    __syncthreads();
#pragma unroll
    for (int i = 0; i < 4; i++) {
        int yy = y + i * 8;
        dst[(size_t)(d0 + yy) * NS + s0 + x] = tile[x][yy];
    }
}

// ---------------- flash attention, split-KV x2, BKV=64 ----------------
// grid (64 = qtr*2+split, h=4, b=2), block 256 (4 waves x 16 q-rows).
#define BQ 64
#define BKV 64
#define KPAD 264   // 256+8 elems; 528B (b128-aligned, 2-way banks only)
#define VPAD 72    // 64+8 elems; 144B
#define PPAD 72

__global__ __launch_bounds__(256, 2) void flash_attn2(const ushort_t* __restrict__ Q,
                                                      const ushort_t* __restrict__ K,
                                                      const ushort_t* __restrict__ Vt,
                                                      ushort_t* __restrict__ Opart,
                                                      float* __restrict__ ml) {
    __shared__ ushort_t sK[BKV * KPAD];        // [key][d]     33.8 KB
    __shared__ ushort_t sV[DHEAD * VPAD];      // [d][key]     36.9 KB
    __shared__ ushort_t sP[4][16 * PPAD];      // per-wave [row][key] 9.2 KB

    const int qtr = blockIdx.x >> 1, split = blockIdx.x & 1;
    const int qt = 31 - qtr;                   // big q-tiles dispatch first
    const int h = blockIdx.y, b = blockIdx.z;
    const int t = threadIdx.x, w = t >> 6, l = t & 63;
    const int lc = l & 15, lq = l >> 4;
    const int bh = b * NHEADS + h;
    const size_t base = (size_t)bh * NS * DHEAD;
    const int q0 = qt * BQ;
    const int qrow_g = q0 + w * 16 + lq * 4;   // +r = this lane's rows

    const int nch = qt + 1;                    // 64-key chunks in causal range
    const int cmid = (nch + 1) >> 1;
    const int cbeg = split ? cmid : 0;
    const int cend = split ? nch : cmid;

    // Q fragments in registers: wave w covers q-rows [q0+w*16, +16)
    bf16x8 qf[8];
    {
        const ushort_t* qrow = Q + base + (size_t)(q0 + w * 16 + lc) * DHEAD + lq * 8;
#pragma unroll
        for (int dk = 0; dk < 8; dk++) qf[dk] = *(const bf16x8*)(qrow + dk * 32);
    }

    floatx4 accO[16];
#pragma unroll
    for (int j = 0; j < 16; j++) accO[j] = (floatx4){0.f, 0.f, 0.f, 0.f};
    float mrun[4], lrun[4];
#pragma unroll
    for (int r = 0; r < 4; r++) { mrun[r] = -__builtin_inff(); lrun[r] = 0.f; }

    for (int kc = cbeg; kc < cend; kc++) {
        const int kb = kc * BKV;
        __syncthreads();
        // stage K chunk: 64 rows x 256 d (8 shortx8 per thread, 512B rows)
#pragma unroll
        for (int j = 0; j < 8; j++) {
            int c = t + j * 256;
            int krow = c >> 5, cc = (c & 31) * 8;
            const ushort_t* g = K + base + (size_t)(kb + krow) * DHEAD + cc;
            *(shortx8*)&sK[krow * KPAD + cc] = *(const shortx8*)g;
        }
        // stage Vt chunk: 256 d-rows x 64 keys
#pragma unroll
        for (int j = 0; j < 8; j++) {
            int c = t + j * 256;
            int drow = c >> 3, cc = (c & 7) * 8;
            const ushort_t* g = Vt + base + (size_t)drow * NS + kb + cc;
            *(shortx8*)&sV[drow * VPAD + cc] = *(const shortx8*)g;
        }
        __syncthreads();

        // S = Q K^T (16 x 64): 4 independent 8-deep MFMA chains
        floatx4 sfr[4];
#pragma unroll
        for (int g = 0; g < 4; g++) sfr[g] = (floatx4){0.f, 0.f, 0.f, 0.f};
#pragma unroll
        for (int dk = 0; dk < 8; dk++) {
#pragma unroll
            for (int g = 0; g < 4; g++) {
                bf16x8 bk = *(const bf16x8*)&sK[(g * 16 + lc) * KPAD + dk * 32 + lq * 8];
                sfr[g] = mfma16(qf[dk], bk, sfr[g]);
            }
        }
        // causal mask — only the diagonal chunk needs it (kc == qt)
        if (kc == nch - 1) {
#pragma unroll
            for (int g = 0; g < 4; g++) {
                int kg = kb + g * 16 + lc;
#pragma unroll
                for (int r = 0; r < 4; r++)
                    if (kg > qrow_g + r) sfr[g][r] = -1e30f;
            }
        }
        // online softmax (rows live across 16 lanes of a quad)
        float mch[4];
#pragma unroll
        for (int r = 0; r < 4; r++)
            mch[r] = fmaxf(fmaxf(sfr[0][r], sfr[1][r]), fmaxf(sfr[2][r], sfr[3][r]));
#pragma unroll
        for (int off = 1; off < 16; off <<= 1)
#pragma unroll
            for (int r = 0; r < 4; r++) mch[r] = fmaxf(mch[r], __shfl_xor(mch[r], off));
        float alpha[4], psum[4], p[4][4];
#pragma unroll
        for (int r = 0; r < 4; r++) {
            float mnew = fmaxf(mrun[r], mch[r]);
            alpha[r] = __expf(mrun[r] - mnew);
            mrun[r] = mnew;
            psum[r] = 0.f;
#pragma unroll
            for (int g = 0; g < 4; g++) {
                p[g][r] = __expf(sfr[g][r] - mnew);
                psum[r] += p[g][r];
            }
        }
#pragma unroll
        for (int off = 1; off < 16; off <<= 1)
#pragma unroll
            for (int r = 0; r < 4; r++) psum[r] += __shfl_xor(psum[r], off);
#pragma unroll
        for (int r = 0; r < 4; r++) lrun[r] = lrun[r] * alpha[r] + psum[r];
#pragma unroll
        for (int j = 0; j < 16; j++)
#pragma unroll
            for (int r = 0; r < 4; r++) accO[j][r] *= alpha[r];

        // P: C-layout -> LDS -> A-layout (per-wave buffer, wave-internal ordering)
        ushort_t* pw = sP[w];
#pragma unroll
        for (int g = 0; g < 4; g++)
#pragma unroll
            for (int r = 0; r < 4; r++)
                pw[(lq * 4 + r) * PPAD + g * 16 + lc] = f2bf(p[g][r]);
        bf16x8 ap0 = *(const bf16x8*)&pw[lc * PPAD + lq * 8];
        bf16x8 ap1 = *(const bf16x8*)&pw[lc * PPAD + 32 + lq * 8];
        // O += P V  (two 32-key MFMA steps per d-frag)
#pragma unroll
        for (int j = 0; j < 16; j++) {
            bf16x8 bv0 = *(const bf16x8*)&sV[(j * 16 + lc) * VPAD + lq * 8];
            bf16x8 bv1 = *(const bf16x8*)&sV[(j * 16 + lc) * VPAD + 32 + lq * 8];
            accO[j] = mfma16(ap0, bv0, accO[j]);
            accO[j] = mfma16(ap1, bv1, accO[j]);
        }
    }

    // epilogue: write unnormalized partial O (bf16) + m/l
    const int pid = (bh * 32 + qt) * 2 + split;
    ushort_t* op = Opart + (size_t)pid * (64 * 256);
#pragma unroll
    for (int r = 0; r < 4; r++) {
        int row = w * 16 + lq * 4 + r;
#pragma unroll
        for (int j = 0; j < 16; j++)
            op[row * 256 + j * 16 + lc] = f2bf(accO[j][r]);
    }
    if (lc == 0) {
#pragma unroll
        for (int r = 0; r < 4; r++) {
            int row = w * 16 + lq * 4 + r;
            ml[(size_t)pid * 128 + row] = mrun[r];
            ml[(size_t)pid * 128 + 64 + row] = lrun[r];
        }
    }
}

// ---------------- combine split-KV partials -> O[b][s][h][d] bf16 ----------------
__global__ __launch_bounds__(256) void combine_splits(const ushort_t* __restrict__ Opart,
                                                      const float* __restrict__ ml,
                                                      ushort_t* __restrict__ O) {
    const int qt = blockIdx.x, h = blockIdx.y, b = blockIdx.z;
    const int bh = b * NHEADS + h;
    const int pid0 = (bh * 32 + qt) * 2;
    const ushort_t* O0 = Opart + (size_t)pid0 * (64 * 256);
    const ushort_t* O1 = O0 + 64 * 256;
    const int col = threadIdx.x;
    for (int row = 0; row < 64; row++) {
        float m0 = ml[(size_t)pid0 * 128 + row];
        float l0 = ml[(size_t)pid0 * 128 + 64 + row];
        float m1 = ml[(size_t)(pid0 + 1) * 128 + row];
        float l1 = ml[(size_t)(pid0 + 1) * 128 + 64 + row];
        float M = fmaxf(m0, m1);
        float w0 = __expf(m0 - M), w1 = __expf(m1 - M);
        float inv = 1.f / (l0 * w0 + l1 * w1);
        float v = (bf2f(O0[row * 256 + col]) * w0 + bf2f(O1[row * 256 + col]) * w1) * inv;
        int s = qt * 64 + row;
        O[((size_t)(b * NS + s) * NHEADS + h) * DHEAD + col] = f2bf(v);
    }
}

// ---------------- launch ----------------
extern "C" void kernel_launch(void* const* d_in, const int* in_sizes, int n_in,
                              void* d_out, int out_size, void* d_ws, size_t ws_size,
                              hipStream_t stream) {
    const float* hidden = (const float*)d_in[0];
    const float* fre = (const float*)d_in[1];
    const float* fim = (const float*)d_in[2];
    // d_in[3] = mask (causal, reproduced analytically)
    const float* Wqkv = (const float*)d_in[4];
    const float* Wo = (const float*)d_in[5];

    char* ws = (char*)d_ws;
    ushort_t* hb    = (ushort_t*)(ws);                 // [0,8)    4096x1024 bf16
    ushort_t* wqkvb = (ushort_t*)(ws + 8388608);       // [8,14)   3072x1024 bf16
    ushort_t* wob   = (ushort_t*)(ws + 14680064);      // [14,16)  1024x1024 bf16
    ushort_t* qkvb  = (ushort_t*)(ws + 16777216);      // [16,40)  dead after rope
    ushort_t* vtb   = (ushort_t*)(ws + 16777216);      // [16,24)  alias over qkvb
    ushort_t* Opart = (ushort_t*)(ws + 25165824);      // [24,40)  alias: 512*64*256 bf16 = 16MB
    ushort_t* qb    = (ushort_t*)(ws + 41943040);      // [40,48)  dead after flash
    ushort_t* oattn = (ushort_t*)(ws + 41943040);      // [40,48)  alias over qb
    ushort_t* kb    = (ushort_t*)(ws + 50331648);      // [48,56)
    ushort_t* vb    = (ushort_t*)(ws + 58720256);      // [56,64)
    float*    ml    = (float*)(ws + 67108864);         // [64,64.25) 512*128 fp32

    cast_kernel<<<4096, 256, 0, stream>>>(hidden, hb, 4096 * 1024 / 4);
    cast_kernel<<<3072, 256, 0, stream>>>(Wqkv, wqkvb, 3072 * 1024 / 4);
    cast_kernel<<<1024, 256, 0, stream>>>(Wo, wob, 1024 * 1024 / 4);

    gemm_bt<true><<<dim3(3072 / 128, 4096 / 128), 256, 0, stream>>>(
        hb, wqkvb, qkvb, 4096, 3072, 1024);

    rope_split<<<4096, 256, 0, stream>>>(qkvb, fre, fim, qb, kb, vb);
    transpose_v<<<dim3(64, 8, 8), 256, 0, stream>>>(vb, vtb);

    flash_attn2<<<dim3(64, NHEADS, NB), 256, 0, stream>>>(qb, kb, vtb, Opart, ml);
    combine_splits<<<dim3(32, NHEADS, NB), 256, 0, stream>>>(Opart, ml, oattn);

    gemm_bt<false><<<dim3(1024 / 128, 4096 / 128), 256, 0, stream>>>(
        oattn, wob, d_out, 4096, 1024, 1024);
}